// Round 9
// baseline (236.390 us; speedup 1.0000x reference)
//
#include <hip/hip_runtime.h>
#include <hip/hip_fp16.h>

#define N_NODES 100000
#define E_EDGES 1600000
#define IN_C 128
#define HID_C 64
#define OUT_C 32
#define BNODES 64                                   // nodes per bucket (dst>>6)
#define NBUCK ((N_NODES + BNODES - 1) / BNODES)     // 1563
#define MAXB 2048                                   // bucket cap (mean 1024, sigma~32)
#define NCHUNK 256                                  // edge chunks (privatized sort)
#define CHUNK_E (E_EDGES / NCHUNK)                  // 6250
#define SCAN_N (NBUCK * NCHUNK)                     // 400128 counts
#define SCAN_NB (SCAN_N / 256)                      // 1563 blocks (also: bsums[i] pairs with hist row i)

// chunk<->block swizzle: consecutive chunks land on the same XCD (blockIdx%8 heuristic),
// so adjacent pairs-windows (shared 64B lines) merge in one L2 instead of ping-ponging.
__device__ __forceinline__ int chunk_of_block(int b) { return (b & 7) * (NCHUNK / 8) + (b >> 3); }

// ---- chunk histogram: block k histograms its 6250-edge slice in LDS (1024 thr) ----
__global__ __launch_bounds__(1024) void chunk_hist_kernel(const int* __restrict__ dst,
                                                          int* __restrict__ hist) {
    __shared__ int h[NBUCK];
    for (int i = threadIdx.x; i < NBUCK; i += 1024) h[i] = 0;
    __syncthreads();
    const int chunk = chunk_of_block(blockIdx.x);
    const int base = chunk * CHUNK_E;
    for (int j = threadIdx.x; j < CHUNK_E; j += 1024)
        atomicAdd(&h[dst[base + j] >> 6], 1);
    __syncthreads();
    for (int i = threadIdx.x; i < NBUCK; i += 1024)
        hist[i * NCHUNK + chunk] = h[i];
}

// ---- scan stage 1: per-256-block exclusive scan; block sums out.
//      NOTE: consumers add bsums[] themselves — there is no scan3 pass. ----
__global__ void scan1_kernel(int* __restrict__ data, int* __restrict__ bsums) {
    __shared__ int s[256];
    int i = blockIdx.x * 256 + threadIdx.x;
    int v = data[i];
    s[threadIdx.x] = v;
    __syncthreads();
    for (int off = 1; off < 256; off <<= 1) {
        int t = (threadIdx.x >= off) ? s[threadIdx.x - off] : 0;
        __syncthreads();
        s[threadIdx.x] += t;
        __syncthreads();
    }
    data[i] = s[threadIdx.x] - v;                   // exclusive within block
    if (threadIdx.x == 255) bsums[blockIdx.x] = s[255];
}

// ---- scan stage 2: exclusive scan of the 1563 block sums (single block, 2 passes) ----
__global__ __launch_bounds__(1024) void scan2_kernel(int* __restrict__ bsums) {
    __shared__ int s[1024];
    int total = 0;
    for (int base = 0; base < SCAN_NB; base += 1024) {
        int i = base + threadIdx.x;
        int v = (i < SCAN_NB) ? bsums[i] : 0;
        s[threadIdx.x] = v;
        __syncthreads();
        for (int off = 1; off < 1024; off <<= 1) {
            int t = (threadIdx.x >= off) ? s[threadIdx.x - off] : 0;
            __syncthreads();
            s[threadIdx.x] += t;
            __syncthreads();
        }
        if (i < SCAN_NB) bsums[i] = total + s[threadIdx.x] - v;
        total += s[1023];
        __syncthreads();
    }
}

// ---- chunk fill: block k scatters its slice into PRIVATE windows.
//      Global offset of (bucket i, chunk) = hist[i*256+chunk] + bsums[i]  (scan3 folded in). ----
__global__ __launch_bounds__(1024) void chunk_fill_kernel(const int* __restrict__ src,
                                                          const int* __restrict__ dst,
                                                          const int* __restrict__ hist,
                                                          const int* __restrict__ bsums,
                                                          unsigned* __restrict__ pairs) {
    __shared__ int cur[NBUCK];
    const int chunk = chunk_of_block(blockIdx.x);
    for (int i = threadIdx.x; i < NBUCK; i += 1024)
        cur[i] = hist[i * NCHUNK + chunk] + bsums[i];
    __syncthreads();
    const int base = chunk * CHUNK_E;
    for (int j = threadIdx.x; j < CHUNK_E; j += 1024) {
        int d = dst[base + j];
        int pos = atomicAdd(&cur[d >> 6], 1);
        pairs[pos] = ((unsigned)src[base + j] << 6) | (unsigned)(d & 63);
    }
}

// ---- per-bucket counting sort -> node-level CSR, in place (LDS stage) ----
__global__ __launch_bounds__(256) void bucket_sort_kernel(const int* __restrict__ hist,
                                                          const int* __restrict__ bsums,
                                                          unsigned* __restrict__ pairs,
                                                          int* __restrict__ row_ptr,
                                                          float* __restrict__ dinv) {
    __shared__ unsigned sp[MAXB];
    __shared__ int hcnt[BNODES], scn[BNODES], cur[BNODES];
    const int b = blockIdx.x;
    const int beg = hist[b * NCHUNK] + bsums[b];
    const int end = (b + 1 < NBUCK) ? hist[(b + 1) * NCHUNK] + bsums[b + 1] : E_EDGES;
    const int cnt = end - beg;
    if (threadIdx.x < BNODES) hcnt[threadIdx.x] = 0;
    __syncthreads();
    for (int j = threadIdx.x; j < cnt; j += 256) {
        unsigned p = pairs[beg + j];
        sp[j] = p;
        atomicAdd(&hcnt[p & 63], 1);
    }
    __syncthreads();
    if (threadIdx.x < BNODES) scn[threadIdx.x] = hcnt[threadIdx.x];
    __syncthreads();
    for (int off = 1; off < BNODES; off <<= 1) {
        int t = 0;
        if (threadIdx.x < BNODES && threadIdx.x >= off) t = scn[threadIdx.x - off];
        __syncthreads();
        if (threadIdx.x < BNODES) scn[threadIdx.x] += t;
        __syncthreads();
    }
    if (threadIdx.x < BNODES) {
        int ex = scn[threadIdx.x] - hcnt[threadIdx.x];   // exclusive
        cur[threadIdx.x] = ex;
        int node = b * BNODES + threadIdx.x;
        if (node < N_NODES) {
            row_ptr[node] = beg + ex;
            dinv[node] = rsqrtf((float)hcnt[threadIdx.x] + 1.0f);
        }
    }
    if (threadIdx.x == 0 && b == NBUCK - 1) row_ptr[N_NODES] = E_EDGES;
    __syncthreads();
    for (int j = threadIdx.x; j < cnt; j += 256) {
        unsigned p = sp[j];
        int pos = atomicAdd(&cur[p & 63], 1);
        pairs[beg + pos] = p >> 6;                      // now plain src index
    }
}

// ---- hs(fp16) = dinv[row] * (x @ W1) : register-tiled 8 rows x 8 cols per thread.
//      8 rows halves LDS W-traffic per FMA vs 4 rows. 256 rows/block, grid 391. ----
__global__ __launch_bounds__(256) void gemm1_kernel(const float* __restrict__ x,
                                                    const float* __restrict__ W1,
                                                    const float* __restrict__ dinv,
                                                    __half* __restrict__ hs) {
    __shared__ float sW[IN_C * HID_C];
    for (int i = threadIdx.x; i < IN_C * HID_C; i += 256) sW[i] = W1[i];
    __syncthreads();
    const int cg = (threadIdx.x & 7) * 8;
    const int row0 = blockIdx.x * 256 + (threadIdx.x >> 3) * 8;
    float acc[8][8];
#pragma unroll
    for (int r = 0; r < 8; ++r)
#pragma unroll
        for (int c = 0; c < 8; ++c) acc[r][c] = 0.f;

    int rr[8];
#pragma unroll
    for (int r = 0; r < 8; ++r) rr[r] = min(row0 + r, N_NODES - 1);

    const float4* x4 = (const float4*)x;
    for (int k4 = 0; k4 < IN_C / 4; ++k4) {
        float4 xv[8];
#pragma unroll
        for (int r = 0; r < 8; ++r) xv[r] = x4[(size_t)rr[r] * (IN_C / 4) + k4];
        float xs[8][4];
#pragma unroll
        for (int r = 0; r < 8; ++r) {
            xs[r][0] = xv[r].x; xs[r][1] = xv[r].y; xs[r][2] = xv[r].z; xs[r][3] = xv[r].w;
        }
#pragma unroll
        for (int kk = 0; kk < 4; ++kk) {
            const float4* wp = (const float4*)(sW + (k4 * 4 + kk) * HID_C + cg);
            float4 w0 = wp[0], w1 = wp[1];
            float wv[8] = {w0.x, w0.y, w0.z, w0.w, w1.x, w1.y, w1.z, w1.w};
#pragma unroll
            for (int r = 0; r < 8; ++r)
#pragma unroll
                for (int c = 0; c < 8; ++c)
                    acc[r][c] = fmaf(xs[r][kk], wv[c], acc[r][c]);
        }
    }
#pragma unroll
    for (int r = 0; r < 8; ++r) {
        int row = row0 + r;
        if (row < N_NODES) {
            float dv = dinv[row];
            union { float4 f; __half2 h[4]; } u;
#pragma unroll
            for (int q = 0; q < 4; ++q)
                u.h[q] = __floats2half2_rn(acc[r][2 * q] * dv, acc[r][2 * q + 1] * dv);
            *(float4*)(hs + (size_t)row * HID_C + cg) = u.f;   // 16 B packed store
        }
    }
}

// ---- layer-1 aggregate: 32 lanes x half2 per node (2 nodes/wave), CSR pull, fp16 gather.
//      Output h2 now fp16 (half2 store) — halves gemm2's input traffic. ----
__global__ void agg1_kernel(const int* __restrict__ row_ptr, const int* __restrict__ col,
                            const __half2* __restrict__ hs2, const float* __restrict__ dinv,
                            const float* __restrict__ b1, __half2* __restrict__ h2h) {
    const int node = blockIdx.x * 8 + (threadIdx.x >> 5);
    const int c2 = threadIdx.x & 31;               // half2 index: channels 2*c2, 2*c2+1
    if (node >= N_NODES) return;
    const int beg = row_ptr[node], end = row_ptr[node + 1];
    float2 f = __half22float2(hs2[node * 32 + c2]);   // self loop
    float ax = f.x, ay = f.y;
    int j = beg;
    for (; j + 7 < end; j += 8) {                  // 8 independent gathers in flight
        int s0 = col[j],     s1 = col[j + 1], s2 = col[j + 2], s3 = col[j + 3];
        int s4 = col[j + 4], s5 = col[j + 5], s6 = col[j + 6], s7 = col[j + 7];
        float2 v0 = __half22float2(hs2[s0 * 32 + c2]);
        float2 v1 = __half22float2(hs2[s1 * 32 + c2]);
        float2 v2 = __half22float2(hs2[s2 * 32 + c2]);
        float2 v3 = __half22float2(hs2[s3 * 32 + c2]);
        float2 v4 = __half22float2(hs2[s4 * 32 + c2]);
        float2 v5 = __half22float2(hs2[s5 * 32 + c2]);
        float2 v6 = __half22float2(hs2[s6 * 32 + c2]);
        float2 v7 = __half22float2(hs2[s7 * 32 + c2]);
        ax += ((v0.x + v1.x) + (v2.x + v3.x)) + ((v4.x + v5.x) + (v6.x + v7.x));
        ay += ((v0.y + v1.y) + (v2.y + v3.y)) + ((v4.y + v5.y) + (v6.y + v7.y));
    }
    for (; j + 1 < end; j += 2) {
        int s0 = col[j], s1 = col[j + 1];
        float2 v0 = __half22float2(hs2[s0 * 32 + c2]);
        float2 v1 = __half22float2(hs2[s1 * 32 + c2]);
        ax += v0.x + v1.x; ay += v0.y + v1.y;
    }
    if (j < end) {
        float2 v = __half22float2(hs2[col[j] * 32 + c2]);
        ax += v.x; ay += v.y;
    }
    float dv = dinv[node];
    float2 bb = ((const float2*)b1)[c2];
    h2h[node * 32 + c2] = __floats2half2_rn(fmaxf(dv * ax + bb.x, 0.f),
                                            fmaxf(dv * ay + bb.y, 0.f));
}

// ---- gs(fp16) = dinv[row] * (h2(fp16) @ W2) : 4 rows x 8 cols per thread, 256 rows/block ----
__global__ __launch_bounds__(256) void gemm2_kernel(const __half* __restrict__ h2h,
                                                    const float* __restrict__ W2,
                                                    const float* __restrict__ dinv,
                                                    __half* __restrict__ gs) {
    __shared__ float sW[HID_C * OUT_C];
    for (int i = threadIdx.x; i < HID_C * OUT_C; i += 256) sW[i] = W2[i];
    __syncthreads();
    const int cg = (threadIdx.x & 3) * 8;
    const int row0 = blockIdx.x * 256 + (threadIdx.x >> 2) * 4;
    float acc[4][8];
#pragma unroll
    for (int r = 0; r < 4; ++r)
#pragma unroll
        for (int c = 0; c < 8; ++c) acc[r][c] = 0.f;

    int rr[4];
#pragma unroll
    for (int r = 0; r < 4; ++r) rr[r] = min(row0 + r, N_NODES - 1);

    const float4* h4 = (const float4*)h2h;          // 8 halves per float4
    for (int k8 = 0; k8 < HID_C / 8; ++k8) {        // 8 iterations
        float xs[4][8];
#pragma unroll
        for (int r = 0; r < 4; ++r) {
            union { float4 f; __half2 h[4]; } u;
            u.f = h4[(size_t)rr[r] * (HID_C / 8) + k8];
#pragma unroll
            for (int q = 0; q < 4; ++q) {
                float2 v = __half22float2(u.h[q]);
                xs[r][2 * q] = v.x; xs[r][2 * q + 1] = v.y;
            }
        }
#pragma unroll
        for (int kk = 0; kk < 8; ++kk) {
            const float4* wp = (const float4*)(sW + (k8 * 8 + kk) * OUT_C + cg);
            float4 w0 = wp[0], w1 = wp[1];
            float wv[8] = {w0.x, w0.y, w0.z, w0.w, w1.x, w1.y, w1.z, w1.w};
#pragma unroll
            for (int r = 0; r < 4; ++r)
#pragma unroll
                for (int c = 0; c < 8; ++c)
                    acc[r][c] = fmaf(xs[r][kk], wv[c], acc[r][c]);
        }
    }
#pragma unroll
    for (int r = 0; r < 4; ++r) {
        int row = row0 + r;
        if (row < N_NODES) {
            float dv = dinv[row];
            union { float4 f; __half2 h[4]; } u;
#pragma unroll
            for (int q = 0; q < 4; ++q)
                u.h[q] = __floats2half2_rn(acc[r][2 * q] * dv, acc[r][2 * q + 1] * dv);
            *(float4*)(gs + (size_t)row * OUT_C + cg) = u.f;
        }
    }
}

// ---- layer-2 aggregate: 16 lanes x half2 per node (4 nodes/wave), CSR pull, fp16 gather ----
__global__ void agg2_kernel(const int* __restrict__ row_ptr, const int* __restrict__ col,
                            const __half2* __restrict__ gs2, const float* __restrict__ dinv,
                            const float* __restrict__ b2, float* __restrict__ out) {
    const int node = blockIdx.x * 16 + (threadIdx.x >> 4);
    const int c2 = threadIdx.x & 15;               // half2 index: channels 2*c2, 2*c2+1
    if (node >= N_NODES) return;
    const int beg = row_ptr[node], end = row_ptr[node + 1];
    float2 f = __half22float2(gs2[node * 16 + c2]);   // self loop
    float ax = f.x, ay = f.y;
    int j = beg;
    for (; j + 7 < end; j += 8) {
        int s0 = col[j],     s1 = col[j + 1], s2 = col[j + 2], s3 = col[j + 3];
        int s4 = col[j + 4], s5 = col[j + 5], s6 = col[j + 6], s7 = col[j + 7];
        float2 v0 = __half22float2(gs2[s0 * 16 + c2]);
        float2 v1 = __half22float2(gs2[s1 * 16 + c2]);
        float2 v2 = __half22float2(gs2[s2 * 16 + c2]);
        float2 v3 = __half22float2(gs2[s3 * 16 + c2]);
        float2 v4 = __half22float2(gs2[s4 * 16 + c2]);
        float2 v5 = __half22float2(gs2[s5 * 16 + c2]);
        float2 v6 = __half22float2(gs2[s6 * 16 + c2]);
        float2 v7 = __half22float2(gs2[s7 * 16 + c2]);
        ax += ((v0.x + v1.x) + (v2.x + v3.x)) + ((v4.x + v5.x) + (v6.x + v7.x));
        ay += ((v0.y + v1.y) + (v2.y + v3.y)) + ((v4.y + v5.y) + (v6.y + v7.y));
    }
    for (; j + 1 < end; j += 2) {
        int s0 = col[j], s1 = col[j + 1];
        float2 v0 = __half22float2(gs2[s0 * 16 + c2]);
        float2 v1 = __half22float2(gs2[s1 * 16 + c2]);
        ax += v0.x + v1.x; ay += v0.y + v1.y;
    }
    if (j < end) {
        float2 v = __half22float2(gs2[col[j] * 16 + c2]);
        ax += v.x; ay += v.y;
    }
    float dv = dinv[node];
    float2 bb = ((const float2*)b2)[c2];
    float2 o;
    o.x = dv * ax + bb.x;
    o.y = dv * ay + bb.y;
    ((float2*)out)[node * 16 + c2] = o;
}

extern "C" void kernel_launch(void* const* d_in, const int* in_sizes, int n_in,
                              void* d_out, int out_size, void* d_ws, size_t ws_size,
                              hipStream_t stream) {
    const float* x  = (const float*)d_in[0];   // [N,128]
    const int*   ei = (const int*)d_in[1];     // [2,E]
    const float* W1 = (const float*)d_in[2];   // [128,64]
    const float* b1 = (const float*)d_in[3];   // [64]
    const float* W2 = (const float*)d_in[4];   // [64,32]
    const float* b2 = (const float*)d_in[5];   // [32]
    float* out = (float*)d_out;                // [N,32]

    const int* srcv = ei;
    const int* dstv = ei + E_EDGES;

    // workspace layout (~35 MB)
    float* dinv  = (float*)d_ws;                           // N floats
    __half* hs   = (__half*)(dinv + N_NODES);              // N*64 halves (reused as gs)
    __half* h2h  = hs + (size_t)N_NODES * HID_C;           // N*64 halves
    int* hist      = (int*)(h2h + (size_t)N_NODES * HID_C); // NBUCK*NCHUNK (400k)
    int* bsums     = hist + SCAN_N;                        // SCAN_NB (1563)
    int* row_ptr   = bsums + SCAN_NB;                      // N+1
    unsigned* pairs = (unsigned*)(row_ptr + N_NODES + 1);  // E (pairs -> sorted src = col)
    __half* gs = hs;                                       // reuse after agg1
    int* col = (int*)pairs;

    // CSR build: chunk-privatized counting sort (scan3 folded into consumers)
    chunk_hist_kernel<<<NCHUNK, 1024, 0, stream>>>(dstv, hist);
    scan1_kernel<<<SCAN_NB, 256, 0, stream>>>(hist, bsums);
    scan2_kernel<<<1, 1024, 0, stream>>>(bsums);
    chunk_fill_kernel<<<NCHUNK, 1024, 0, stream>>>(srcv, dstv, hist, bsums, pairs);
    bucket_sort_kernel<<<NBUCK, 256, 0, stream>>>(hist, bsums, pairs, row_ptr, dinv);

    // layer 1
    gemm1_kernel<<<(N_NODES + 255) / 256, 256, 0, stream>>>(x, W1, dinv, hs);
    agg1_kernel<<<(N_NODES + 7) / 8, 256, 0, stream>>>(row_ptr, col, (const __half2*)hs,
                                                       dinv, b1, (__half2*)h2h);

    // layer 2
    gemm2_kernel<<<(N_NODES + 255) / 256, 256, 0, stream>>>(h2h, W2, dinv, gs);
    agg2_kernel<<<(N_NODES + 15) / 16, 256, 0, stream>>>(row_ptr, col, (const __half2*)gs,
                                                         dinv, b2, out);
}

// Round 10
// 232.077 us; speedup vs baseline: 1.0186x; 1.0186x over previous
//
#include <hip/hip_runtime.h>
#include <hip/hip_fp16.h>

#define N_NODES 100000
#define E_EDGES 1600000
#define IN_C 128
#define HID_C 64
#define OUT_C 32
#define BNODES 64                                   // nodes per bucket (dst>>6)
#define NBUCK ((N_NODES + BNODES - 1) / BNODES)     // 1563
#define MAXB 2048                                   // bucket cap (mean 1024, sigma~32)
#define NCHUNK 256                                  // edge chunks (privatized sort)
#define CHUNK_E (E_EDGES / NCHUNK)                  // 6250
#define SCAN_N (NBUCK * NCHUNK)                     // 400128 counts
#define SCAN_NB (SCAN_N / 256)                      // 1563 blocks (bsums[i] pairs with hist row i)

// chunk<->block swizzle: consecutive chunks land on the same XCD (blockIdx%8 heuristic),
// so adjacent pairs-windows (shared 64B lines) merge in one L2 instead of ping-ponging.
__device__ __forceinline__ int chunk_of_block(int b) { return (b & 7) * (NCHUNK / 8) + (b >> 3); }

// ---- chunk histogram: block k histograms its 6250-edge slice in LDS (1024 thr) ----
__global__ __launch_bounds__(1024) void chunk_hist_kernel(const int* __restrict__ dst,
                                                          int* __restrict__ hist) {
    __shared__ int h[NBUCK];
    for (int i = threadIdx.x; i < NBUCK; i += 1024) h[i] = 0;
    __syncthreads();
    const int chunk = chunk_of_block(blockIdx.x);
    const int base = chunk * CHUNK_E;
    for (int j = threadIdx.x; j < CHUNK_E; j += 1024)
        atomicAdd(&h[dst[base + j] >> 6], 1);
    __syncthreads();
    for (int i = threadIdx.x; i < NBUCK; i += 1024)
        hist[i * NCHUNK + chunk] = h[i];
}

// ---- scan stage 1: per-256-block exclusive scan; block sums out.
//      Consumers add bsums[] themselves — no scan3 pass. ----
__global__ void scan1_kernel(int* __restrict__ data, int* __restrict__ bsums) {
    __shared__ int s[256];
    int i = blockIdx.x * 256 + threadIdx.x;
    int v = data[i];
    s[threadIdx.x] = v;
    __syncthreads();
    for (int off = 1; off < 256; off <<= 1) {
        int t = (threadIdx.x >= off) ? s[threadIdx.x - off] : 0;
        __syncthreads();
        s[threadIdx.x] += t;
        __syncthreads();
    }
    data[i] = s[threadIdx.x] - v;                   // exclusive within block
    if (threadIdx.x == 255) bsums[blockIdx.x] = s[255];
}

// ---- scan stage 2: exclusive scan of the 1563 block sums (single block, 2 passes) ----
__global__ __launch_bounds__(1024) void scan2_kernel(int* __restrict__ bsums) {
    __shared__ int s[1024];
    int total = 0;
    for (int base = 0; base < SCAN_NB; base += 1024) {
        int i = base + threadIdx.x;
        int v = (i < SCAN_NB) ? bsums[i] : 0;
        s[threadIdx.x] = v;
        __syncthreads();
        for (int off = 1; off < 1024; off <<= 1) {
            int t = (threadIdx.x >= off) ? s[threadIdx.x - off] : 0;
            __syncthreads();
            s[threadIdx.x] += t;
            __syncthreads();
        }
        if (i < SCAN_NB) bsums[i] = total + s[threadIdx.x] - v;
        total += s[1023];
        __syncthreads();
    }
}

// ---- chunk fill: block k scatters its slice into PRIVATE windows.
//      Global offset of (bucket i, chunk) = hist[i*256+chunk] + bsums[i]. ----
__global__ __launch_bounds__(1024) void chunk_fill_kernel(const int* __restrict__ src,
                                                          const int* __restrict__ dst,
                                                          const int* __restrict__ hist,
                                                          const int* __restrict__ bsums,
                                                          unsigned* __restrict__ pairs) {
    __shared__ int cur[NBUCK];
    const int chunk = chunk_of_block(blockIdx.x);
    for (int i = threadIdx.x; i < NBUCK; i += 1024)
        cur[i] = hist[i * NCHUNK + chunk] + bsums[i];
    __syncthreads();
    const int base = chunk * CHUNK_E;
    for (int j = threadIdx.x; j < CHUNK_E; j += 1024) {
        int d = dst[base + j];
        int pos = atomicAdd(&cur[d >> 6], 1);
        pairs[pos] = ((unsigned)src[base + j] << 6) | (unsigned)(d & 63);
    }
}

// ---- per-bucket counting sort -> node-level CSR, in place (LDS stage) ----
__global__ __launch_bounds__(256) void bucket_sort_kernel(const int* __restrict__ hist,
                                                          const int* __restrict__ bsums,
                                                          unsigned* __restrict__ pairs,
                                                          int* __restrict__ row_ptr,
                                                          float* __restrict__ dinv) {
    __shared__ unsigned sp[MAXB];
    __shared__ int hcnt[BNODES], scn[BNODES], cur[BNODES];
    const int b = blockIdx.x;
    const int beg = hist[b * NCHUNK] + bsums[b];
    const int end = (b + 1 < NBUCK) ? hist[(b + 1) * NCHUNK] + bsums[b + 1] : E_EDGES;
    const int cnt = end - beg;
    if (threadIdx.x < BNODES) hcnt[threadIdx.x] = 0;
    __syncthreads();
    for (int j = threadIdx.x; j < cnt; j += 256) {
        unsigned p = pairs[beg + j];
        sp[j] = p;
        atomicAdd(&hcnt[p & 63], 1);
    }
    __syncthreads();
    if (threadIdx.x < BNODES) scn[threadIdx.x] = hcnt[threadIdx.x];
    __syncthreads();
    for (int off = 1; off < BNODES; off <<= 1) {
        int t = 0;
        if (threadIdx.x < BNODES && threadIdx.x >= off) t = scn[threadIdx.x - off];
        __syncthreads();
        if (threadIdx.x < BNODES) scn[threadIdx.x] += t;
        __syncthreads();
    }
    if (threadIdx.x < BNODES) {
        int ex = scn[threadIdx.x] - hcnt[threadIdx.x];   // exclusive
        cur[threadIdx.x] = ex;
        int node = b * BNODES + threadIdx.x;
        if (node < N_NODES) {
            row_ptr[node] = beg + ex;
            dinv[node] = rsqrtf((float)hcnt[threadIdx.x] + 1.0f);
        }
    }
    if (threadIdx.x == 0 && b == NBUCK - 1) row_ptr[N_NODES] = E_EDGES;
    __syncthreads();
    for (int j = threadIdx.x; j < cnt; j += 256) {
        unsigned p = sp[j];
        int pos = atomicAdd(&cur[p & 63], 1);
        pairs[beg + pos] = p >> 6;                      // now plain src index
    }
}

// ---- hs(fp16) = dinv[row] * (x @ W1) : 4 rows x 8 cols per thread, 128 rows/block.
//      grid 782 (~3 blocks/CU) — 8-row/256-block variant halves occupancy and runs 2x
//      slower from whole-CU imbalance (round-9 counters: Occ 10.8%, 46 us). ----
__global__ __launch_bounds__(256) void gemm1_kernel(const float* __restrict__ x,
                                                    const float* __restrict__ W1,
                                                    const float* __restrict__ dinv,
                                                    __half* __restrict__ hs) {
    __shared__ float sW[IN_C * HID_C];
    for (int i = threadIdx.x; i < IN_C * HID_C; i += 256) sW[i] = W1[i];
    __syncthreads();
    const int cg = (threadIdx.x & 7) * 8;
    const int row0 = blockIdx.x * 128 + (threadIdx.x >> 3) * 4;
    float acc[4][8];
#pragma unroll
    for (int r = 0; r < 4; ++r)
#pragma unroll
        for (int c = 0; c < 8; ++c) acc[r][c] = 0.f;

    int rr[4];
#pragma unroll
    for (int r = 0; r < 4; ++r) rr[r] = min(row0 + r, N_NODES - 1);

    const float4* x4 = (const float4*)x;
#pragma unroll 2
    for (int k4 = 0; k4 < IN_C / 4; ++k4) {
        float4 xv[4];
#pragma unroll
        for (int r = 0; r < 4; ++r) xv[r] = x4[(size_t)rr[r] * (IN_C / 4) + k4];
        float xs[4][4];
#pragma unroll
        for (int r = 0; r < 4; ++r) {
            xs[r][0] = xv[r].x; xs[r][1] = xv[r].y; xs[r][2] = xv[r].z; xs[r][3] = xv[r].w;
        }
#pragma unroll
        for (int kk = 0; kk < 4; ++kk) {
            const float4* wp = (const float4*)(sW + (k4 * 4 + kk) * HID_C + cg);
            float4 w0 = wp[0], w1 = wp[1];
            float wv[8] = {w0.x, w0.y, w0.z, w0.w, w1.x, w1.y, w1.z, w1.w};
#pragma unroll
            for (int r = 0; r < 4; ++r)
#pragma unroll
                for (int c = 0; c < 8; ++c)
                    acc[r][c] = fmaf(xs[r][kk], wv[c], acc[r][c]);
        }
    }
#pragma unroll
    for (int r = 0; r < 4; ++r) {
        int row = row0 + r;
        if (row < N_NODES) {
            float dv = dinv[row];
            union { float4 f; __half2 h[4]; } u;
#pragma unroll
            for (int q = 0; q < 4; ++q)
                u.h[q] = __floats2half2_rn(acc[r][2 * q] * dv, acc[r][2 * q + 1] * dv);
            *(float4*)(hs + (size_t)row * HID_C + cg) = u.f;   // 16 B packed store
        }
    }
}

// ---- layer-1 aggregate: 32 lanes x half2 per node (2 nodes/wave), CSR pull, fp16 gather.
//      Output h2 fp16 (half2 store). ----
__global__ void agg1_kernel(const int* __restrict__ row_ptr, const int* __restrict__ col,
                            const __half2* __restrict__ hs2, const float* __restrict__ dinv,
                            const float* __restrict__ b1, __half2* __restrict__ h2h) {
    const int node = blockIdx.x * 8 + (threadIdx.x >> 5);
    const int c2 = threadIdx.x & 31;               // half2 index: channels 2*c2, 2*c2+1
    if (node >= N_NODES) return;
    const int beg = row_ptr[node], end = row_ptr[node + 1];
    float2 f = __half22float2(hs2[node * 32 + c2]);   // self loop
    float ax = f.x, ay = f.y;
    int j = beg;
    for (; j + 7 < end; j += 8) {                  // 8 independent gathers in flight
        int s0 = col[j],     s1 = col[j + 1], s2 = col[j + 2], s3 = col[j + 3];
        int s4 = col[j + 4], s5 = col[j + 5], s6 = col[j + 6], s7 = col[j + 7];
        float2 v0 = __half22float2(hs2[s0 * 32 + c2]);
        float2 v1 = __half22float2(hs2[s1 * 32 + c2]);
        float2 v2 = __half22float2(hs2[s2 * 32 + c2]);
        float2 v3 = __half22float2(hs2[s3 * 32 + c2]);
        float2 v4 = __half22float2(hs2[s4 * 32 + c2]);
        float2 v5 = __half22float2(hs2[s5 * 32 + c2]);
        float2 v6 = __half22float2(hs2[s6 * 32 + c2]);
        float2 v7 = __half22float2(hs2[s7 * 32 + c2]);
        ax += ((v0.x + v1.x) + (v2.x + v3.x)) + ((v4.x + v5.x) + (v6.x + v7.x));
        ay += ((v0.y + v1.y) + (v2.y + v3.y)) + ((v4.y + v5.y) + (v6.y + v7.y));
    }
    for (; j + 1 < end; j += 2) {
        int s0 = col[j], s1 = col[j + 1];
        float2 v0 = __half22float2(hs2[s0 * 32 + c2]);
        float2 v1 = __half22float2(hs2[s1 * 32 + c2]);
        ax += v0.x + v1.x; ay += v0.y + v1.y;
    }
    if (j < end) {
        float2 v = __half22float2(hs2[col[j] * 32 + c2]);
        ax += v.x; ay += v.y;
    }
    float dv = dinv[node];
    float2 bb = ((const float2*)b1)[c2];
    h2h[node * 32 + c2] = __floats2half2_rn(fmaxf(dv * ax + bb.x, 0.f),
                                            fmaxf(dv * ay + bb.y, 0.f));
}

// ---- gs(fp16) = dinv[row] * (h2(fp16) @ W2) : 2 rows x 8 cols per thread, 128 rows/block ----
__global__ __launch_bounds__(256) void gemm2_kernel(const __half* __restrict__ h2h,
                                                    const float* __restrict__ W2,
                                                    const float* __restrict__ dinv,
                                                    __half* __restrict__ gs) {
    __shared__ float sW[HID_C * OUT_C];
    for (int i = threadIdx.x; i < HID_C * OUT_C; i += 256) sW[i] = W2[i];
    __syncthreads();
    const int cg = (threadIdx.x & 3) * 8;
    const int row0 = blockIdx.x * 128 + (threadIdx.x >> 2) * 2;
    float acc[2][8];
#pragma unroll
    for (int r = 0; r < 2; ++r)
#pragma unroll
        for (int c = 0; c < 8; ++c) acc[r][c] = 0.f;

    int rr[2];
#pragma unroll
    for (int r = 0; r < 2; ++r) rr[r] = min(row0 + r, N_NODES - 1);

    const float4* h4 = (const float4*)h2h;          // 8 halves per float4
    for (int k8 = 0; k8 < HID_C / 8; ++k8) {        // 8 iterations
        float xs[2][8];
#pragma unroll
        for (int r = 0; r < 2; ++r) {
            union { float4 f; __half2 h[4]; } u;
            u.f = h4[(size_t)rr[r] * (HID_C / 8) + k8];
#pragma unroll
            for (int q = 0; q < 4; ++q) {
                float2 v = __half22float2(u.h[q]);
                xs[r][2 * q] = v.x; xs[r][2 * q + 1] = v.y;
            }
        }
#pragma unroll
        for (int kk = 0; kk < 8; ++kk) {
            const float4* wp = (const float4*)(sW + (k8 * 8 + kk) * OUT_C + cg);
            float4 w0 = wp[0], w1 = wp[1];
            float wv[8] = {w0.x, w0.y, w0.z, w0.w, w1.x, w1.y, w1.z, w1.w};
#pragma unroll
            for (int r = 0; r < 2; ++r)
#pragma unroll
                for (int c = 0; c < 8; ++c)
                    acc[r][c] = fmaf(xs[r][kk], wv[c], acc[r][c]);
        }
    }
#pragma unroll
    for (int r = 0; r < 2; ++r) {
        int row = row0 + r;
        if (row < N_NODES) {
            float dv = dinv[row];
            union { float4 f; __half2 h[4]; } u;
#pragma unroll
            for (int q = 0; q < 4; ++q)
                u.h[q] = __floats2half2_rn(acc[r][2 * q] * dv, acc[r][2 * q + 1] * dv);
            *(float4*)(gs + (size_t)row * OUT_C + cg) = u.f;
        }
    }
}

// ---- layer-2 aggregate: 16 lanes x half2 per node (4 nodes/wave), CSR pull, fp16 gather ----
__global__ void agg2_kernel(const int* __restrict__ row_ptr, const int* __restrict__ col,
                            const __half2* __restrict__ gs2, const float* __restrict__ dinv,
                            const float* __restrict__ b2, float* __restrict__ out) {
    const int node = blockIdx.x * 16 + (threadIdx.x >> 4);
    const int c2 = threadIdx.x & 15;               // half2 index: channels 2*c2, 2*c2+1
    if (node >= N_NODES) return;
    const int beg = row_ptr[node], end = row_ptr[node + 1];
    float2 f = __half22float2(gs2[node * 16 + c2]);   // self loop
    float ax = f.x, ay = f.y;
    int j = beg;
    for (; j + 7 < end; j += 8) {
        int s0 = col[j],     s1 = col[j + 1], s2 = col[j + 2], s3 = col[j + 3];
        int s4 = col[j + 4], s5 = col[j + 5], s6 = col[j + 6], s7 = col[j + 7];
        float2 v0 = __half22float2(gs2[s0 * 16 + c2]);
        float2 v1 = __half22float2(gs2[s1 * 16 + c2]);
        float2 v2 = __half22float2(gs2[s2 * 16 + c2]);
        float2 v3 = __half22float2(gs2[s3 * 16 + c2]);
        float2 v4 = __half22float2(gs2[s4 * 16 + c2]);
        float2 v5 = __half22float2(gs2[s5 * 16 + c2]);
        float2 v6 = __half22float2(gs2[s6 * 16 + c2]);
        float2 v7 = __half22float2(gs2[s7 * 16 + c2]);
        ax += ((v0.x + v1.x) + (v2.x + v3.x)) + ((v4.x + v5.x) + (v6.x + v7.x));
        ay += ((v0.y + v1.y) + (v2.y + v3.y)) + ((v4.y + v5.y) + (v6.y + v7.y));
    }
    for (; j + 1 < end; j += 2) {
        int s0 = col[j], s1 = col[j + 1];
        float2 v0 = __half22float2(gs2[s0 * 16 + c2]);
        float2 v1 = __half22float2(gs2[s1 * 16 + c2]);
        ax += v0.x + v1.x; ay += v0.y + v1.y;
    }
    if (j < end) {
        float2 v = __half22float2(gs2[col[j] * 16 + c2]);
        ax += v.x; ay += v.y;
    }
    float dv = dinv[node];
    float2 bb = ((const float2*)b2)[c2];
    float2 o;
    o.x = dv * ax + bb.x;
    o.y = dv * ay + bb.y;
    ((float2*)out)[node * 16 + c2] = o;
}

extern "C" void kernel_launch(void* const* d_in, const int* in_sizes, int n_in,
                              void* d_out, int out_size, void* d_ws, size_t ws_size,
                              hipStream_t stream) {
    const float* x  = (const float*)d_in[0];   // [N,128]
    const int*   ei = (const int*)d_in[1];     // [2,E]
    const float* W1 = (const float*)d_in[2];   // [128,64]
    const float* b1 = (const float*)d_in[3];   // [64]
    const float* W2 = (const float*)d_in[4];   // [64,32]
    const float* b2 = (const float*)d_in[5];   // [32]
    float* out = (float*)d_out;                // [N,32]

    const int* srcv = ei;
    const int* dstv = ei + E_EDGES;

    // workspace layout (~35 MB)
    float* dinv  = (float*)d_ws;                           // N floats
    __half* hs   = (__half*)(dinv + N_NODES);              // N*64 halves (reused as gs)
    __half* h2h  = hs + (size_t)N_NODES * HID_C;           // N*64 halves
    int* hist      = (int*)(h2h + (size_t)N_NODES * HID_C); // NBUCK*NCHUNK (400k)
    int* bsums     = hist + SCAN_N;                        // SCAN_NB (1563)
    int* row_ptr   = bsums + SCAN_NB;                      // N+1
    unsigned* pairs = (unsigned*)(row_ptr + N_NODES + 1);  // E (pairs -> sorted src = col)
    __half* gs = hs;                                       // reuse after agg1
    int* col = (int*)pairs;

    // CSR build: chunk-privatized counting sort (scan3 folded into consumers)
    chunk_hist_kernel<<<NCHUNK, 1024, 0, stream>>>(dstv, hist);
    scan1_kernel<<<SCAN_NB, 256, 0, stream>>>(hist, bsums);
    scan2_kernel<<<1, 1024, 0, stream>>>(bsums);
    chunk_fill_kernel<<<NCHUNK, 1024, 0, stream>>>(srcv, dstv, hist, bsums, pairs);
    bucket_sort_kernel<<<NBUCK, 256, 0, stream>>>(hist, bsums, pairs, row_ptr, dinv);

    // layer 1
    gemm1_kernel<<<(N_NODES + 127) / 128, 256, 0, stream>>>(x, W1, dinv, hs);
    agg1_kernel<<<(N_NODES + 7) / 8, 256, 0, stream>>>(row_ptr, col, (const __half2*)hs,
                                                       dinv, b1, (__half2*)h2h);

    // layer 2
    gemm2_kernel<<<(N_NODES + 127) / 128, 256, 0, stream>>>(h2h, W2, dinv, gs);
    agg2_kernel<<<(N_NODES + 15) / 16, 256, 0, stream>>>(row_ptr, col, (const __half2*)gs,
                                                         dinv, b2, out);
}